// Round 2
// baseline (162.842 us; speedup 1.0000x reference)
//
#include <hip/hip_runtime.h>

// Problem geometry (compile-time constants from the reference)
#define N_TOTAL 500000
#define C 128
#define G 32
#define CG 4          // channels per group
#define NB 8          // clouds
#define EPS 1e-5f

// cumulative boundaries of LENGTHS = {40000,55000,70000,45000,80000,65000,90000,55000}
__device__ __forceinline__ int cloud_of(int i) {
    int c = 0;
    c += (i >= 40000);
    c += (i >= 95000);
    c += (i >= 165000);
    c += (i >= 210000);
    c += (i >= 290000);
    c += (i >= 355000);
    c += (i >= 445000);
    return c;
}

// element counts per (cloud, group) = LENGTHS[b] * CG
__device__ const float d_cnt[NB] = {160000.f, 220000.f, 280000.f, 180000.f,
                                    320000.f, 260000.f, 360000.f, 220000.f};

// ws layout: ws[0..255] = sum[cloud][group], ws[256..511] = sumsq[cloud][group]
__global__ void gn_zero(float* __restrict__ ws) {
    int i = threadIdx.x;
    if (i < 2 * NB * G) ws[i] = 0.f;
}

// Pass 1: per-(cloud,group) sum & sumsq.
// 32 threads per row (each thread = one group = float4), 8 rows per 256-thread block iter.
__global__ __launch_bounds__(256) void gn_stats(const float* __restrict__ feats,
                                                const int* __restrict__ perm,
                                                float* __restrict__ ws,
                                                int rows_per_block) {
    __shared__ float lacc[2 * NB * G];   // [0..255]=sum, [256..511]=sumsq
    int tid = threadIdx.x;
    for (int idx = tid; idx < 2 * NB * G; idx += 256) lacc[idx] = 0.f;
    __syncthreads();

    const int g = tid & 31;      // group / float4 index within row
    const int rsub = tid >> 5;   // 0..7 row within iteration
    int start = blockIdx.x * rows_per_block;
    int end = start + rows_per_block;
    if (end > N_TOTAL) end = N_TOTAL;

    float s = 0.f, ss = 0.f;
    int cur = -1;
    for (int row = start + rsub; row < end; row += 8) {
        int cl = cloud_of(row);
        if (cl != cur) {
            if (cur >= 0 && (s != 0.f || ss != 0.f)) {
                atomicAdd(&lacc[cur * G + g], s);
                atomicAdd(&lacc[NB * G + cur * G + g], ss);
            }
            cur = cl; s = 0.f; ss = 0.f;
        }
        int p = perm[row];
        const float4* rp = (const float4*)(feats + ((long long)p << 7));
        float4 v = rp[g];
        s  += v.x + v.y + v.z + v.w;
        ss += v.x * v.x + v.y * v.y + v.z * v.z + v.w * v.w;
    }
    if (cur >= 0 && (s != 0.f || ss != 0.f)) {
        atomicAdd(&lacc[cur * G + g], s);
        atomicAdd(&lacc[NB * G + cur * G + g], ss);
    }
    __syncthreads();

    for (int idx = tid; idx < 2 * NB * G; idx += 256) {
        float a = lacc[idx];
        if (a != 0.f) atomicAdd(&ws[idx], a);
    }
}

// Pass 2: finalize stats in LDS, then normalize + affine, scatter to out[perm[i]].
__global__ __launch_bounds__(256) void gn_apply(const float* __restrict__ feats,
                                                const float* __restrict__ gamma,
                                                const float* __restrict__ beta,
                                                const int* __restrict__ perm,
                                                const float* __restrict__ ws,
                                                float* __restrict__ out) {
    __shared__ float lmean[NB * G];
    __shared__ float linv[NB * G];
    int tid = threadIdx.x;
    for (int idx = tid; idx < NB * G; idx += 256) {
        float s = ws[idx];
        float ss = ws[NB * G + idx];
        float cnt = d_cnt[idx >> 5];
        float m = s / cnt;
        float var = ss / cnt - m * m;
        lmean[idx] = m;
        linv[idx] = rsqrtf(var + EPS);
    }
    __syncthreads();

    const int g = tid & 31;
    const int rsub = tid >> 5;
    float4 gm = ((const float4*)gamma)[g];
    float4 bt = ((const float4*)beta)[g];

    int stride = gridDim.x * 8;
    for (int row = blockIdx.x * 8 + rsub; row < N_TOTAL; row += stride) {
        int cl = cloud_of(row);
        int p = perm[row];
        const float4* rp = (const float4*)(feats + ((long long)p << 7));
        float4 v = rp[g];
        float m = lmean[cl * G + g];
        float inv = linv[cl * G + g];
        // y = (v - m) * inv * gamma + beta
        float4 y;
        y.x = (v.x - m) * inv * gm.x + bt.x;
        y.y = (v.y - m) * inv * gm.y + bt.y;
        y.z = (v.z - m) * inv * gm.z + bt.z;
        y.w = (v.w - m) * inv * gm.w + bt.w;
        ((float4*)(out + ((long long)p << 7)))[g] = y;
    }
}

extern "C" void kernel_launch(void* const* d_in, const int* in_sizes, int n_in,
                              void* d_out, int out_size, void* d_ws, size_t ws_size,
                              hipStream_t stream) {
    const float* feats = (const float*)d_in[0];
    const float* gamma = (const float*)d_in[1];
    const float* beta  = (const float*)d_in[2];
    const int*   perm  = (const int*)d_in[3];
    float* out = (float*)d_out;
    float* ws  = (float*)d_ws;

    gn_zero<<<1, 512, 0, stream>>>(ws);

    const int nblk = 2048;
    int rpb = (N_TOTAL + nblk - 1) / nblk;  // 245 rows per block
    gn_stats<<<nblk, 256, 0, stream>>>(feats, perm, ws, rpb);
    gn_apply<<<nblk, 256, 0, stream>>>(feats, gamma, beta, perm, ws, out);
}